// Round 1
// baseline (152.916 us; speedup 1.0000x reference)
//
#include <hip/hip_runtime.h>

// Problem constants (B=4, C=3 -> BC=12 classes)
#define BC 12
#define NP 1024          // predicted vertices per class
#define NG 2048          // GT points per class
#define NP1 1025         // N+1
#define MAT_STRIDE ((size_t)NP1 * NP1)   // 1050625
#define THR_F 0.05590169943749474f

// ws layout:
//   closs_part : 192 doubles  @ 0
//   mloss_part : 192 doubles  @ 1536
//   w_ins      : BC*NP ints   @ 3072
//   w_key      : BC*NP i64    @ 3072 + 49152 = 52224 (8-aligned)
#define WS_CLOSS 0
#define WS_MLOSS 1536
#define WS_INS   3072
#define WS_KEY   52224

// ---------------------------------------------------------------------------
// Kernel 1: per-pred nearest GT, matched-instance/key tables, closs partials.
// grid = 192 blocks (12 classes x 16 chunks of 64 preds), block = 256.
// Each pred is handled by 4 consecutive lanes, each scanning 512 GT points.
// ---------------------------------------------------------------------------
__global__ __launch_bounds__(256) void nearest_kernel(
    const float* __restrict__ positions,   // [BC, NP, 3]
    const float* __restrict__ gt_pts,      // [BC, NG, 2]
    const int* __restrict__ gt_ins,        // [BC, NG]
    const int* __restrict__ gt_order,      // [BC, NG]
    int* __restrict__ w_ins,               // [BC, NP]
    long long* __restrict__ w_key,         // [BC, NP]
    double* __restrict__ closs_part)       // [192]
{
    __shared__ float2 s_gt[NG];            // normalized GT, 16 KB
    __shared__ double s_red[4];

    const int bx = blockIdx.x;
    const int c = bx >> 4;                 // class
    const int base = (bx & 15) * 64;       // first pred of this block
    const int tid = threadIdx.x;

    // stage normalized GT points into LDS
    for (int p = tid; p < NG; p += 256) {
        float gx = gt_pts[((size_t)c * NG + p) * 2 + 0];
        float gy = gt_pts[((size_t)c * NG + p) * 2 + 1];
        // (gt + bound) / (2*bound), plain f32 ops (no contraction possible)
        s_gt[p] = make_float2((gx + 30.0f) / 60.0f, (gy + 15.0f) / 30.0f);
    }
    __syncthreads();

    const int i = base + (tid >> 2);       // pred index within class
    const int part = tid & 3;              // which quarter of GT this lane scans

    const float px = positions[((size_t)c * NP + i) * 3 + 0];
    const float py = positions[((size_t)c * NP + i) * 3 + 1];

    float bd = 3.4e38f;
    int bi = 0;
    const int p0 = part * 512;
#pragma unroll 4
    for (int p = p0; p < p0 + 512; ++p) {
        float2 g = s_gt[p];
        float dx = px - g.x;
        float dy = py - g.y;
        // no-FMA d2 to match the numpy reference bit pattern
        float d2 = __fadd_rn(__fmul_rn(dx, dx), __fmul_rn(dy, dy));
        if (d2 < bd) { bd = d2; bi = p; }   // strict < => first index on ties
    }
    // combine the 4 partial scans (lexicographic (d2, idx) min => first-index tiebreak)
    for (int m = 1; m <= 2; m <<= 1) {
        float od = __shfl_xor(bd, m);
        int   oi = __shfl_xor(bi, m);
        if (od < bd || (od == bd && oi < bi)) { bd = od; bi = oi; }
    }

    double contrib = 0.0;
    if (part == 0) {
        float nd = __fsqrt_rn(fmaxf(bd, 1e-12f));
        int matched = nd < THR_F;
        int insv = matched ? gt_ins[(size_t)c * NG + bi] : -1;
        int ordv = gt_order[(size_t)c * NG + bi];
        w_ins[(size_t)c * NP + i] = insv;
        w_key[(size_t)c * NP + i] = ((long long)ordv << 10) | (long long)i;
        float2 g = s_gt[bi];
        contrib = (double)fabsf(px - g.x) + (double)fabsf(py - g.y);
    }

    // block-reduce closs contribution (f64)
    for (int off = 32; off; off >>= 1) contrib += __shfl_down(contrib, off);
    if ((tid & 63) == 0) s_red[tid >> 6] = contrib;
    __syncthreads();
    if (tid == 0)
        closs_part[bx] = s_red[0] + s_red[1] + s_red[2] + s_red[3];
}

// ---------------------------------------------------------------------------
// Kernel 2: successor/predecessor within instance, scatter match_gt ones,
// gather logm for mloss partials.
// grid = 192 blocks (12 classes x 16 chunks of 64 preds), block = 256.
// 4 lanes per pred, each scanning 256 of the 1024 candidates.
// ---------------------------------------------------------------------------
__global__ __launch_bounds__(256) void links_kernel(
    const float* __restrict__ matches,     // [BC, NP1, NP1] log-probs
    const int* __restrict__ w_ins,
    const long long* __restrict__ w_key,
    float* __restrict__ out,               // full output buffer
    double* __restrict__ mloss_part)       // [192]
{
    __shared__ int       s_ins[NP];        // 4 KB
    __shared__ long long s_key[NP];        // 8 KB
    __shared__ double s_red[4];

    const int bx = blockIdx.x;
    const int c = bx >> 4;
    const int base = (bx & 15) * 64;
    const int tid = threadIdx.x;

    for (int j = tid; j < NP; j += 256) {
        s_ins[j] = w_ins[(size_t)c * NP + j];
        s_key[j] = w_key[(size_t)c * NP + j];
    }
    __syncthreads();

    const int i = base + (tid >> 2);
    const int part = tid & 3;

    const int ins = s_ins[i];
    const long long ki = s_key[i];

    long long succ = 0x7FFFFFFFFFFFFFFFLL;   // min over keys > ki
    long long prdk = -1LL;                   // max over keys < ki
    if (ins >= 0) {
        const int j0 = part * 256;
        for (int j = j0; j < j0 + 256; ++j) {
            if (s_ins[j] == ins) {
                long long kj = s_key[j];
                if (kj > ki && kj < succ) succ = kj;
                if (kj < ki && kj > prdk) prdk = kj;
            }
        }
    }
    for (int m = 1; m <= 2; m <<= 1) {
        long long os = __shfl_xor(succ, m);
        long long op = __shfl_xor(prdk, m);
        if (os < succ) succ = os;
        if (op > prdk) prdk = op;
    }

    double s = 0.0;
    if (part == 0) {
        int fwd = (succ == 0x7FFFFFFFFFFFFFFFLL) ? NP : (int)(succ & 1023);
        int bwd = (prdk < 0) ? NP : (int)(prdk & 1023);
        float* mgt = out + 2 + (size_t)c * MAT_STRIDE;
        mgt[(size_t)i * NP1 + fwd] = 1.0f;           // row i -> fwd (or bin col)
        if (bwd == NP)
            mgt[(size_t)NP * NP1 + i] = 1.0f;        // bin row -> col i
        const float* lm = matches + (size_t)c * MAT_STRIDE;
        s = (double)lm[(size_t)i * NP1 + fwd] + (double)lm[(size_t)i * NP1 + bwd];
    }

    for (int off = 32; off; off >>= 1) s += __shfl_down(s, off);
    if ((tid & 63) == 0) s_red[tid >> 6] = s;
    __syncthreads();
    if (tid == 0)
        mloss_part[bx] = s_red[0] + s_red[1] + s_red[2] + s_red[3];
}

// ---------------------------------------------------------------------------
// Kernel 3: reduce partials -> closs, mloss scalars.
// ---------------------------------------------------------------------------
__global__ __launch_bounds__(256) void finalize_kernel(
    const double* __restrict__ closs_part,
    const double* __restrict__ mloss_part,
    float* __restrict__ out)
{
    __shared__ double sc[4], sm[4];
    const int t = threadIdx.x;
    double cs = 0.0, ms = 0.0;
    for (int i = t; i < 192; i += 256) { cs += closs_part[i]; ms += mloss_part[i]; }
    for (int off = 32; off; off >>= 1) {
        cs += __shfl_down(cs, off);
        ms += __shfl_down(ms, off);
    }
    if ((t & 63) == 0) { sc[t >> 6] = cs; sm[t >> 6] = ms; }
    __syncthreads();
    if (t == 0) {
        double C = sc[0] + sc[1] + sc[2] + sc[3];
        double M = sm[0] + sm[1] + sm[2] + sm[3];
        out[0] = (float)(C / (12.0 * 2048.0));       // mean over classes of mean |pos-gt|
        out[1] = (float)(-M / (12.0 * 1024.0));      // -(mean fwd + mean bwd) over classes
    }
}

extern "C" void kernel_launch(void* const* d_in, const int* in_sizes, int n_in,
                              void* d_out, int out_size, void* d_ws, size_t ws_size,
                              hipStream_t stream) {
    const float* matches   = (const float*)d_in[0];
    const float* positions = (const float*)d_in[1];
    // d_in[2] = masks (all ones, unused)
    const float* gt_pts    = (const float*)d_in[3];
    const int*   gt_ins    = (const int*)d_in[4];
    const int*   gt_order  = (const int*)d_in[5];
    float* out = (float*)d_out;

    char* ws = (char*)d_ws;
    double*    closs_part = (double*)(ws + WS_CLOSS);
    double*    mloss_part = (double*)(ws + WS_MLOSS);
    int*       w_ins      = (int*)(ws + WS_INS);
    long long* w_key      = (long long*)(ws + WS_KEY);

    // zero the entire output (match_gt is sparse ones over a zero matrix)
    hipMemsetAsync(d_out, 0, (size_t)out_size * sizeof(float), stream);

    nearest_kernel<<<dim3(192), dim3(256), 0, stream>>>(
        positions, gt_pts, gt_ins, gt_order, w_ins, w_key, closs_part);
    links_kernel<<<dim3(192), dim3(256), 0, stream>>>(
        matches, w_ins, w_key, out, mloss_part);
    finalize_kernel<<<dim3(1), dim3(256), 0, stream>>>(
        closs_part, mloss_part, out);
}

// Round 2
// 140.270 us; speedup vs baseline: 1.0902x; 1.0902x over previous
//
#include <hip/hip_runtime.h>

// Problem constants (B=4, C=3 -> BC=12 classes)
#define BC 12
#define NP 1024          // predicted vertices per class
#define NG 2048          // GT points per class
#define NP1 1025         // N+1
#define MAT_STRIDE ((size_t)NP1 * NP1)   // 1050625
#define THR_F 0.05590169943749474f
#define NBLK 768         // 12 classes x 64 chunks of 16 preds
#define KEY_BIG (1 << 26)

// ws layout:
//   closs_part : 768 doubles @ 0      (6144 B)
//   mloss_part : 768 doubles @ 6144   (6144 B)
//   w_key      : BC*NP ints  @ 12288  (49152 B)
#define WS_CLOSS 0
#define WS_MLOSS 6144
#define WS_KEY   12288

// ---------------------------------------------------------------------------
// Kernel 1: per-pred nearest GT -> packed key table + closs partials.
// grid = 768 (12 classes x 64 chunks of 16 preds), block = 256.
// 16 lanes per pred, each scanning 64 float4s (128 GT points) from LDS.
// ---------------------------------------------------------------------------
__global__ __launch_bounds__(256) void nearest_kernel(
    const float* __restrict__ positions,   // [BC, NP, 3]
    const float* __restrict__ gt_pts,      // [BC, NG, 2]
    const int* __restrict__ gt_ins,        // [BC, NG]
    const int* __restrict__ gt_order,      // [BC, NG]
    int* __restrict__ w_key,               // [BC, NP] packed (ins<<15)|(ord<<10)|i
    double* __restrict__ closs_part)       // [768]
{
    __shared__ float4 s_gt[NG / 2];        // 2 normalized points per float4, 16 KB
    __shared__ double s_red[4];

    const int bx = blockIdx.x;
    const int c = bx >> 6;                 // class
    const int base = (bx & 63) * 16;       // first pred of this block
    const int tid = threadIdx.x;

    // stage + normalize GT points (vectorized: 2 points per float4)
    const float4* gsrc = (const float4*)(gt_pts + (size_t)c * NG * 2);
    for (int p = tid; p < NG / 2; p += 256) {
        float4 g = gsrc[p];
        g.x = (g.x + 30.0f) / 60.0f;
        g.y = (g.y + 15.0f) / 30.0f;
        g.z = (g.z + 30.0f) / 60.0f;
        g.w = (g.w + 15.0f) / 30.0f;
        s_gt[p] = g;
    }
    __syncthreads();

    const int i = base + (tid >> 4);       // pred index within class
    const int part = tid & 15;             // 16-way split of the GT scan

    const float px = positions[((size_t)c * NP + i) * 3 + 0];
    const float py = positions[((size_t)c * NP + i) * 3 + 1];

    float bd = 3.4e38f;
    int bi = 0;
    const int q0 = part * 64;
#pragma unroll 8
    for (int q = q0; q < q0 + 64; ++q) {
        float4 g = s_gt[q];
        float dx0 = px - g.x, dy0 = py - g.y;
        // no-FMA d2 to match the numpy reference bit pattern
        float d20 = __fadd_rn(__fmul_rn(dx0, dx0), __fmul_rn(dy0, dy0));
        if (d20 < bd) { bd = d20; bi = 2 * q; }       // strict < => first index
        float dx1 = px - g.z, dy1 = py - g.w;
        float d21 = __fadd_rn(__fmul_rn(dx1, dx1), __fmul_rn(dy1, dy1));
        if (d21 < bd) { bd = d21; bi = 2 * q + 1; }
    }
    // lexicographic (d2, idx) min across the 16 lanes of this pred
    for (int m = 1; m <= 8; m <<= 1) {
        float od = __shfl_xor(bd, m);
        int   oi = __shfl_xor(bi, m);
        if (od < bd || (od == bd && oi < bi)) { bd = od; bi = oi; }
    }

    double contrib = 0.0;
    if (part == 0) {
        float nd = __fsqrt_rn(fmaxf(bd, 1e-12f));
        int key;
        if (nd < THR_F) {
            int insv = gt_ins[(size_t)c * NG + bi];
            int ordv = gt_order[(size_t)c * NG + bi];
            key = (insv << 15) | (ordv << 10) | i;    // matched: < 2^21
        } else {
            key = KEY_BIG | i;                        // unmatched: sorts after all
        }
        w_key[(size_t)c * NP + i] = key;
        float4 g = s_gt[bi >> 1];
        float gx = (bi & 1) ? g.z : g.x;
        float gy = (bi & 1) ? g.w : g.y;
        contrib = (double)fabsf(px - gx) + (double)fabsf(py - gy);
    }

    // block-reduce closs contribution (f64)
    for (int off = 32; off; off >>= 1) contrib += __shfl_down(contrib, off);
    if ((tid & 63) == 0) s_red[tid >> 6] = contrib;
    __syncthreads();
    if (tid == 0)
        closs_part[bx] = s_red[0] + s_red[1] + s_red[2] + s_red[3];
}

// ---------------------------------------------------------------------------
// Kernel 2: successor/predecessor in global key order, scatter match_gt ones,
// gather logm for mloss partials.
// grid = 768, block = 256; 16 lanes per pred, each scanning 16 int4s (64 keys).
// ---------------------------------------------------------------------------
__global__ __launch_bounds__(256) void links_kernel(
    const float* __restrict__ matches,     // [BC, NP1, NP1] log-probs
    const int* __restrict__ w_key,
    float* __restrict__ out,               // full output buffer
    double* __restrict__ mloss_part)       // [768]
{
    __shared__ int s_key[NP];              // 4 KB
    __shared__ double s_red[4];

    const int bx = blockIdx.x;
    const int c = bx >> 6;
    const int base = (bx & 63) * 16;
    const int tid = threadIdx.x;

    // stage the class's key table (256 int4 = 1024 keys)
    ((int4*)s_key)[tid] = ((const int4*)(w_key + (size_t)c * NP))[tid];
    __syncthreads();

    const int i = base + (tid >> 4);
    const int part = tid & 15;
    const int ki = s_key[i];

    int succ = 0x7FFFFFFF;                 // min over keys > ki
    int prd = -1;                          // max over keys < ki
    const int4* sk4 = (const int4*)s_key;
    const int j0 = part * 16;
#pragma unroll 4
    for (int j = j0; j < j0 + 16; ++j) {
        int4 k4 = sk4[j];
        if (k4.x > ki && k4.x < succ) succ = k4.x;
        if (k4.x < ki && k4.x > prd)  prd  = k4.x;
        if (k4.y > ki && k4.y < succ) succ = k4.y;
        if (k4.y < ki && k4.y > prd)  prd  = k4.y;
        if (k4.z > ki && k4.z < succ) succ = k4.z;
        if (k4.z < ki && k4.z > prd)  prd  = k4.z;
        if (k4.w > ki && k4.w < succ) succ = k4.w;
        if (k4.w < ki && k4.w > prd)  prd  = k4.w;
    }
    for (int m = 1; m <= 8; m <<= 1) {
        int os = __shfl_xor(succ, m);
        int op = __shfl_xor(prd, m);
        if (os < succ) succ = os;
        if (op > prd)  prd  = op;
    }

    double s = 0.0;
    if (part == 0) {
        // edge (i -> succ) exists iff same ins field and i's key is matched
        bool fl = (succ != 0x7FFFFFFF) && ((succ >> 15) == (ki >> 15)) && (ki < KEY_BIG);
        int fwd = fl ? (succ & 1023) : NP;
        // edge (prd -> i) exists iff same ins field and prd's key is matched
        bool bl = (prd >= 0) && ((prd >> 15) == (ki >> 15)) && (prd < KEY_BIG);
        int bwd = bl ? (prd & 1023) : NP;

        float* mgt = out + 2 + (size_t)c * MAT_STRIDE;
        mgt[(size_t)i * NP1 + fwd] = 1.0f;           // row i -> fwd (or bin col)
        if (bwd == NP)
            mgt[(size_t)NP * NP1 + i] = 1.0f;        // bin row -> col i
        const float* lm = matches + (size_t)c * MAT_STRIDE;
        s = (double)lm[(size_t)i * NP1 + fwd] + (double)lm[(size_t)i * NP1 + bwd];
    }

    for (int off = 32; off; off >>= 1) s += __shfl_down(s, off);
    if ((tid & 63) == 0) s_red[tid >> 6] = s;
    __syncthreads();
    if (tid == 0)
        mloss_part[bx] = s_red[0] + s_red[1] + s_red[2] + s_red[3];
}

// ---------------------------------------------------------------------------
// Kernel 3: reduce partials -> closs, mloss scalars.
// ---------------------------------------------------------------------------
__global__ __launch_bounds__(256) void finalize_kernel(
    const double* __restrict__ closs_part,
    const double* __restrict__ mloss_part,
    float* __restrict__ out)
{
    __shared__ double sc[4], sm[4];
    const int t = threadIdx.x;
    double cs = 0.0, ms = 0.0;
    for (int i = t; i < NBLK; i += 256) { cs += closs_part[i]; ms += mloss_part[i]; }
    for (int off = 32; off; off >>= 1) {
        cs += __shfl_down(cs, off);
        ms += __shfl_down(ms, off);
    }
    if ((t & 63) == 0) { sc[t >> 6] = cs; sm[t >> 6] = ms; }
    __syncthreads();
    if (t == 0) {
        double C = sc[0] + sc[1] + sc[2] + sc[3];
        double M = sm[0] + sm[1] + sm[2] + sm[3];
        out[0] = (float)(C / (12.0 * 2048.0));       // mean over classes of mean |pos-gt|
        out[1] = (float)(-M / (12.0 * 1024.0));      // -(mean fwd + mean bwd) over classes
    }
}

extern "C" void kernel_launch(void* const* d_in, const int* in_sizes, int n_in,
                              void* d_out, int out_size, void* d_ws, size_t ws_size,
                              hipStream_t stream) {
    const float* matches   = (const float*)d_in[0];
    const float* positions = (const float*)d_in[1];
    // d_in[2] = masks (all ones, unused)
    const float* gt_pts    = (const float*)d_in[3];
    const int*   gt_ins    = (const int*)d_in[4];
    const int*   gt_order  = (const int*)d_in[5];
    float* out = (float*)d_out;

    char* ws = (char*)d_ws;
    double* closs_part = (double*)(ws + WS_CLOSS);
    double* mloss_part = (double*)(ws + WS_MLOSS);
    int*    w_key      = (int*)(ws + WS_KEY);

    // zero the entire output (match_gt is sparse ones over a zero matrix)
    hipMemsetAsync(d_out, 0, (size_t)out_size * sizeof(float), stream);

    nearest_kernel<<<dim3(NBLK), dim3(256), 0, stream>>>(
        positions, gt_pts, gt_ins, gt_order, w_key, closs_part);
    links_kernel<<<dim3(NBLK), dim3(256), 0, stream>>>(
        matches, w_key, out, mloss_part);
    finalize_kernel<<<dim3(1), dim3(256), 0, stream>>>(
        closs_part, mloss_part, out);
}

// Round 3
// 119.731 us; speedup vs baseline: 1.2772x; 1.1715x over previous
//
#include <hip/hip_runtime.h>

// Problem constants (B=4, C=3 -> BC=12 classes)
#define BC 12
#define NP 1024          // predicted vertices per class
#define NG 2048          // GT points per class
#define NP1 1025         // N+1
#define MAT_STRIDE ((size_t)NP1 * NP1)   // 1050625
#define THR_F 0.05590169943749474f
#define NBLK 768         // 12 classes x 64 chunks of 16 preds
#define KEY_BIG (1 << 26)

// ws layout (bytes):
//   closs_part : 768 doubles @ 0       (6144)
//   mloss_part : 768 doubles @ 6144    (6144)
//   w_key      : BC*NP ints  @ 12288   (49152)
//   w_fwd      : BC*NP ints  @ 61440   (49152)
//   w_bwd      : BC*NP ints  @ 110592  (49152)
#define WS_CLOSS 0
#define WS_MLOSS 6144
#define WS_KEY   12288
#define WS_FWD   61440
#define WS_BWD   110592

// ---------------------------------------------------------------------------
// Kernel 1: per-pred nearest GT -> packed key table + closs partials.
// grid = 768 (12 classes x 64 chunks of 16 preds), block = 256.
// 16 lanes per pred; INTERLEAVED scan (q = t*16+part) so LDS word address is
// 64t+4p -> only 2-way bank aliasing (free), vs 16-way for segment-strided.
// ---------------------------------------------------------------------------
__global__ __launch_bounds__(256) void nearest_kernel(
    const float* __restrict__ positions,   // [BC, NP, 3]
    const float* __restrict__ gt_pts,      // [BC, NG, 2]
    const int* __restrict__ gt_ins,        // [BC, NG]
    const int* __restrict__ gt_order,      // [BC, NG]
    int* __restrict__ w_key,               // [BC, NP] packed (ins<<15)|(ord<<10)|i
    double* __restrict__ closs_part)       // [768]
{
    __shared__ float4 s_gt[NG / 2];        // 2 normalized points per float4, 16 KB
    __shared__ double s_red[4];

    const int bx = blockIdx.x;
    const int c = bx >> 6;                 // class
    const int base = (bx & 63) * 16;       // first pred of this block
    const int tid = threadIdx.x;

    // stage + normalize GT points (2 points per float4)
    const float4* gsrc = (const float4*)(gt_pts + (size_t)c * NG * 2);
    for (int p = tid; p < NG / 2; p += 256) {
        float4 g = gsrc[p];
        g.x = (g.x + 30.0f) / 60.0f;
        g.y = (g.y + 15.0f) / 30.0f;
        g.z = (g.z + 30.0f) / 60.0f;
        g.w = (g.w + 15.0f) / 30.0f;
        s_gt[p] = g;
    }
    __syncthreads();

    const int i = base + (tid >> 4);       // pred index within class
    const int part = tid & 15;             // 16-way interleaved split

    const float px = positions[((size_t)c * NP + i) * 3 + 0];
    const float py = positions[((size_t)c * NP + i) * 3 + 1];

    float bd = 3.4e38f;
    int bi = 0;
#pragma unroll 8
    for (int t = 0; t < 64; ++t) {
        const int q = t * 16 + part;       // interleaved: bank-conflict-free
        float4 g = s_gt[q];
        float dx0 = px - g.x, dy0 = py - g.y;
        // no-FMA d2 to match the numpy reference bit pattern
        float d20 = __fadd_rn(__fmul_rn(dx0, dx0), __fmul_rn(dy0, dy0));
        if (d20 < bd) { bd = d20; bi = 2 * q; }       // strict < => first index
        float dx1 = px - g.z, dy1 = py - g.w;
        float d21 = __fadd_rn(__fmul_rn(dx1, dx1), __fmul_rn(dy1, dy1));
        if (d21 < bd) { bd = d21; bi = 2 * q + 1; }
    }
    // lexicographic (d2, idx) min across the 16 lanes of this pred:
    // global first-index tiebreak preserved
    for (int m = 1; m <= 8; m <<= 1) {
        float od = __shfl_xor(bd, m);
        int   oi = __shfl_xor(bi, m);
        if (od < bd || (od == bd && oi < bi)) { bd = od; bi = oi; }
    }

    double contrib = 0.0;
    if (part == 0) {
        float nd = __fsqrt_rn(fmaxf(bd, 1e-12f));
        int key;
        if (nd < THR_F) {
            int insv = gt_ins[(size_t)c * NG + bi];
            int ordv = gt_order[(size_t)c * NG + bi];
            key = (insv << 15) | (ordv << 10) | i;    // matched: < 2^21
        } else {
            key = KEY_BIG | i;                        // unmatched: sorts after all
        }
        w_key[(size_t)c * NP + i] = key;
        float4 g = s_gt[bi >> 1];
        float gx = (bi & 1) ? g.z : g.x;
        float gy = (bi & 1) ? g.w : g.y;
        contrib = (double)fabsf(px - gx) + (double)fabsf(py - gy);
    }

    for (int off = 32; off; off >>= 1) contrib += __shfl_down(contrib, off);
    if ((tid & 63) == 0) s_red[tid >> 6] = contrib;
    __syncthreads();
    if (tid == 0)
        closs_part[bx] = s_red[0] + s_red[1] + s_red[2] + s_red[3];
}

// ---------------------------------------------------------------------------
// Kernel 2: successor/predecessor in global key order -> fwd/bwd tables,
// logm gathers -> mloss partials. grid = 768, block = 256.
// 16 lanes per pred; interleaved int4 scan (j = t*16+part), conflict-free.
// ---------------------------------------------------------------------------
__global__ __launch_bounds__(256) void links_kernel(
    const float* __restrict__ matches,     // [BC, NP1, NP1] log-probs
    const int* __restrict__ w_key,
    int* __restrict__ w_fwd,               // [BC, NP] target col (1024 = bin)
    int* __restrict__ w_bwd,               // [BC, NP] source row (1024 = bin)
    double* __restrict__ mloss_part)       // [768]
{
    __shared__ int s_key[NP];              // 4 KB
    __shared__ double s_red[4];

    const int bx = blockIdx.x;
    const int c = bx >> 6;
    const int base = (bx & 63) * 16;
    const int tid = threadIdx.x;

    ((int4*)s_key)[tid] = ((const int4*)(w_key + (size_t)c * NP))[tid];
    __syncthreads();

    const int i = base + (tid >> 4);
    const int part = tid & 15;
    const int ki = s_key[i];

    int succ = 0x7FFFFFFF;                 // min over keys > ki
    int prd = -1;                          // max over keys < ki
    const int4* sk4 = (const int4*)s_key;
#pragma unroll 4
    for (int t = 0; t < 16; ++t) {
        const int j = t * 16 + part;       // interleaved
        int4 k4 = sk4[j];
        if (k4.x > ki && k4.x < succ) succ = k4.x;
        if (k4.x < ki && k4.x > prd)  prd  = k4.x;
        if (k4.y > ki && k4.y < succ) succ = k4.y;
        if (k4.y < ki && k4.y > prd)  prd  = k4.y;
        if (k4.z > ki && k4.z < succ) succ = k4.z;
        if (k4.z < ki && k4.z > prd)  prd  = k4.z;
        if (k4.w > ki && k4.w < succ) succ = k4.w;
        if (k4.w < ki && k4.w > prd)  prd  = k4.w;
    }
    for (int m = 1; m <= 8; m <<= 1) {
        int os = __shfl_xor(succ, m);
        int op = __shfl_xor(prd, m);
        if (os < succ) succ = os;
        if (op > prd)  prd  = op;
    }

    double s = 0.0;
    if (part == 0) {
        // edge (i -> succ) exists iff same ins field and i's key is matched
        bool fl = (succ != 0x7FFFFFFF) && ((succ >> 15) == (ki >> 15)) && (ki < KEY_BIG);
        int fwd = fl ? (succ & 1023) : NP;
        // edge (prd -> i) exists iff same ins field and prd's key is matched
        bool bl = (prd >= 0) && ((prd >> 15) == (ki >> 15)) && (prd < KEY_BIG);
        int bwd = bl ? (prd & 1023) : NP;

        w_fwd[(size_t)c * NP + i] = fwd;
        w_bwd[(size_t)c * NP + i] = bwd;
        const float* lm = matches + (size_t)c * MAT_STRIDE;
        s = (double)lm[(size_t)i * NP1 + fwd] + (double)lm[(size_t)i * NP1 + bwd];
    }

    for (int off = 32; off; off >>= 1) s += __shfl_down(s, off);
    if ((tid & 63) == 0) s_red[tid >> 6] = s;
    __syncthreads();
    if (tid == 0)
        mloss_part[bx] = s_red[0] + s_red[1] + s_red[2] + s_red[3];
}

// ---------------------------------------------------------------------------
// Kernel 3: write the ENTIRE output (no memset needed). One block per row,
// grid = (1025 rows, 12 classes). Coalesced dword stores; each real row has
// exactly one 1 at fwd; bin row has 1s where bwd==1024. Block (1024, 0)
// additionally reduces the loss partials into out[0], out[1].
// ---------------------------------------------------------------------------
__global__ __launch_bounds__(256) void write_kernel(
    const int* __restrict__ w_fwd,
    const int* __restrict__ w_bwd,
    const double* __restrict__ closs_part,
    const double* __restrict__ mloss_part,
    float* __restrict__ out)
{
    const int r = blockIdx.x;              // row 0..1024
    const int c = blockIdx.y;              // class 0..11
    const int t = threadIdx.x;
    float* row = out + 2 + (size_t)c * MAT_STRIDE + (size_t)r * NP1;

    if (r < NP) {
        const int fwd = w_fwd[c * NP + r]; // uniform scalar load
#pragma unroll
        for (int k = 0; k < 4; ++k) {
            int col = t + 256 * k;
            row[col] = (col == fwd) ? 1.0f : 0.0f;
        }
        if (t == 0) row[1024] = (fwd == NP) ? 1.0f : 0.0f;
    } else {
        // bin row: col j = 1 iff column j has no incoming real edge
#pragma unroll
        for (int k = 0; k < 4; ++k) {
            int col = t + 256 * k;
            row[col] = (w_bwd[c * NP + col] == NP) ? 1.0f : 0.0f;
        }
        if (t == 0) row[1024] = 0.0f;      // (n,n) corner is 0
    }

    if (r == 1024 && c == 0) {
        __shared__ double sc[4], sm[4];
        double cs = 0.0, ms = 0.0;
        for (int i = t; i < NBLK; i += 256) { cs += closs_part[i]; ms += mloss_part[i]; }
        for (int off = 32; off; off >>= 1) {
            cs += __shfl_down(cs, off);
            ms += __shfl_down(ms, off);
        }
        if ((t & 63) == 0) { sc[t >> 6] = cs; sm[t >> 6] = ms; }
        __syncthreads();
        if (t == 0) {
            double C = sc[0] + sc[1] + sc[2] + sc[3];
            double M = sm[0] + sm[1] + sm[2] + sm[3];
            out[0] = (float)(C / (12.0 * 2048.0));   // mean |pos-gt| over all B*C
            out[1] = (float)(-M / (12.0 * 1024.0));  // -(mean fwd + mean bwd)
        }
    }
}

extern "C" void kernel_launch(void* const* d_in, const int* in_sizes, int n_in,
                              void* d_out, int out_size, void* d_ws, size_t ws_size,
                              hipStream_t stream) {
    const float* matches   = (const float*)d_in[0];
    const float* positions = (const float*)d_in[1];
    // d_in[2] = masks (all ones, unused)
    const float* gt_pts    = (const float*)d_in[3];
    const int*   gt_ins    = (const int*)d_in[4];
    const int*   gt_order  = (const int*)d_in[5];
    float* out = (float*)d_out;

    char* ws = (char*)d_ws;
    double* closs_part = (double*)(ws + WS_CLOSS);
    double* mloss_part = (double*)(ws + WS_MLOSS);
    int*    w_key      = (int*)(ws + WS_KEY);
    int*    w_fwd      = (int*)(ws + WS_FWD);
    int*    w_bwd      = (int*)(ws + WS_BWD);

    nearest_kernel<<<dim3(NBLK), dim3(256), 0, stream>>>(
        positions, gt_pts, gt_ins, gt_order, w_key, closs_part);
    links_kernel<<<dim3(NBLK), dim3(256), 0, stream>>>(
        matches, w_key, w_fwd, w_bwd, mloss_part);
    write_kernel<<<dim3(NP1, BC), dim3(256), 0, stream>>>(
        w_fwd, w_bwd, closs_part, mloss_part, out);
}